// Round 9
// baseline (124.110 us; speedup 1.0000x reference)
//
#include <hip/hip_runtime.h>
#include <hip/hip_bf16.h>
#include <math.h>

#define NN     3072
#define NF     128
#define NHID   64
#define HEADS  8
#define LEN    8
#define NPATH  2048
#define NTK    4
#define NELEM  (NPATH*LEN)     // 16384
#define MAXDEG 128
#define SH     16              // 2 sets * 8 heads
#define KSPLIT 8
#define KCH    (NN / KSPLIT)   // 384
#define NDIFB  (KSPLIT * 64)   // 512 diff-GEMM blocks
#define NADV   192             // nlogp tail blocks
#define NNOD   48              // nodeDot tail blocks
#define NDIF   256             // diff_red tail blocks

// ================= kernel 1: GEMM (b<768) + CSR/zeroing (b>=768) =================
__global__ void k_pre(const float* __restrict__ feat,
                      const float* __restrict__ Wp, const float* __restrict__ Ws,
                      const float* __restrict__ ap, const float* __restrict__ as_,
                      const float* __restrict__ adj,
                      float* __restrict__ whg, float* __restrict__ f1g,
                      float* __restrict__ f2g, int* __restrict__ cols,
                      int* __restrict__ cnt, int* __restrict__ hist,
                      int* __restrict__ histT, float* __restrict__ out) {
    __shared__ float Fs[32][68];   // [k][r]
    __shared__ float Wsh[32][64];  // [k][c]
    int b = blockIdx.x;
    int tid = threadIdx.x;
    if (b < 768) {
        int rt = b % 48, sh = b / 48;
        int set = sh >> 3, head = sh & 7;
        int g = sh >> 2, sg = sh & 3;
        const float* W = (set ? Ws : Wp) + (size_t)head * NF * NHID;
        const float* a = (set ? as_ : ap) + (size_t)head * 2 * NHID;
        int tc = (tid & 15) * 4;
        int tr = (tid >> 4) * 4;
        float acc[4][4] = {};
        for (int k0 = 0; k0 < NF; k0 += 32) {
            for (int i = tid; i < 512; i += 256) {
                int r = i >> 3, kq = (i & 7) * 4;
                float4 v = *(const float4*)&feat[(size_t)(rt * 64 + r) * NF + k0 + kq];
                Fs[kq + 0][r] = v.x; Fs[kq + 1][r] = v.y;
                Fs[kq + 2][r] = v.z; Fs[kq + 3][r] = v.w;
            }
            for (int i = tid; i < 512; i += 256) {
                int k = i >> 4, cq = (i & 15) * 4;
                *(float4*)&Wsh[k][cq] = *(const float4*)&W[(size_t)(k0 + k) * NHID + cq];
            }
            __syncthreads();
            #pragma unroll
            for (int k = 0; k < 32; ++k) {
                float4 av = *(const float4*)&Fs[k][tr];
                float4 bv = *(const float4*)&Wsh[k][tc];
                float a_[4] = {av.x, av.y, av.z, av.w};
                float b_[4] = {bv.x, bv.y, bv.z, bv.w};
                #pragma unroll
                for (int i = 0; i < 4; ++i)
                    #pragma unroll
                    for (int j = 0; j < 4; ++j) acc[i][j] += a_[i] * b_[j];
            }
            __syncthreads();
        }
        #pragma unroll
        for (int i = 0; i < 4; ++i)
            *(float4*)&whg[(((size_t)g * NN + rt * 64 + tr + i) * 4 + sg) * NHID + tc] =
                *(float4*)&acc[i][0];
        float4 a1 = *(const float4*)&a[tc];
        float4 a2 = *(const float4*)&a[NHID + tc];
        float p1[4], p2[4];
        #pragma unroll
        for (int i = 0; i < 4; ++i) {
            p1[i] = acc[i][0]*a1.x + acc[i][1]*a1.y + acc[i][2]*a1.z + acc[i][3]*a1.w;
            p2[i] = acc[i][0]*a2.x + acc[i][1]*a2.y + acc[i][2]*a2.z + acc[i][3]*a2.w;
        }
        #pragma unroll
        for (int o = 1; o < 16; o <<= 1) {
            #pragma unroll
            for (int i = 0; i < 4; ++i) {
                p1[i] += __shfl_xor(p1[i], o);
                p2[i] += __shfl_xor(p2[i], o);
            }
        }
        if ((tid & 15) == 0) {
            #pragma unroll
            for (int i = 0; i < 4; ++i) {
                f1g[((size_t)g * NN + rt * 64 + tr + i) * 4 + sg] = p1[i];
                f2g[((size_t)g * NN + rt * 64 + tr + i) * 4 + sg] = p2[i];
            }
        }
        return;
    }
    int cb = b - 768;                      // 0..767
    if (cb < 64) {
        int i = cb * 256 + tid;
        if (i < NN) hist[i] = 0;
        if (i < NN * NTK) histT[i] = 0;
        if (i == 0) { out[NPATH] = 0.f; out[NPATH + 1] = 0.f; }
    }
    int row  = cb * 4 + (tid >> 6);
    int lane = tid & 63;
    const float* ar = adj + (size_t)row * NN;
    int* cr = cols + (size_t)row * MAXDEG;
    int base = 0;
    for (int c0 = 0; c0 < NN; c0 += 256) {
        float4 v = *(const float4*)&ar[c0 + lane * 4];
        float e[4] = {v.x, v.y, v.z, v.w};
        #pragma unroll
        for (int q = 0; q < 4; ++q) {
            bool pred = e[q] > 0.f;
            unsigned long long bb = __ballot(pred);
            int before = __popcll(bb & ((1ull << lane) - 1ull));
            if (pred && (base + before) < MAXDEG) cr[base + before] = c0 + lane * 4 + q;
            base += __popcll(bb);
        }
    }
    if (lane == 0) cnt[row] = base < MAXDEG ? base : MAXDEG;
}

// ================= kernel 2: sparse GAT (all blocks) + path histograms (first 64) =================
__global__ void k_gat(const float* __restrict__ whg, const float* __restrict__ f1g,
                      const float* __restrict__ f2g, const int* __restrict__ cols,
                      const int* __restrict__ cnt, const int* __restrict__ path,
                      const int* __restrict__ task, int* __restrict__ hist,
                      int* __restrict__ histT, float* __restrict__ xo) {
    __shared__ float attT[4][MAXDEG][4];   // 8 KB
    __shared__ int   cls[4][MAXDEG];       // 2 KB
    int b = blockIdx.x;                    // 0..3071
    if (b < 64) {
        int i = b * 256 + threadIdx.x;     // 64*256 == NELEM
        int node = path[i];
        atomicAdd(&hist[node], 1);
        atomicAdd(&histT[node * NTK + task[i]], 1);
    }
    int g = (b & 7) >> 1;                  // sh-group -> XCD pair {2g,2g+1}
    int node4 = ((b >> 3) << 1) | (b & 1);
    int w = threadIdx.x >> 6;
    int lane = threadIdx.x & 63;
    int node = node4 * 4 + w;
    int deg = cnt[node];
    const int* cl = cols + (size_t)node * MAXDEG;
    const float* f2p = f2g + (size_t)g * NN * 4;
    float4 f1q = *(const float4*)&f1g[((size_t)g * NN + node) * 4];
    float f1v[4] = {f1q.x, f1q.y, f1q.z, f1q.w};

    float e0[4], e1[4];
    #pragma unroll
    for (int t = 0; t < 2; ++t) {
        int l = lane + t * 64;
        bool valid = l < deg;
        int j = valid ? cl[l] : 0;
        if (valid) cls[w][l] = j;
        float4 q = *(const float4*)&f2p[(size_t)j * 4];
        float f2v[4] = {q.x, q.y, q.z, q.w};
        float* e = t ? e1 : e0;
        #pragma unroll
        for (int s = 0; s < 4; ++s) {
            float x = f1v[s] + f2v[s];
            x = (x >= 0.f) ? x : 0.2f * x;
            e[s] = valid ? x : -1e30f;
        }
    }
    float m[4], sl[4], inv[4];
    #pragma unroll
    for (int s = 0; s < 4; ++s) m[s] = fmaxf(e0[s], e1[s]);
    #pragma unroll
    for (int o = 32; o; o >>= 1)
        #pragma unroll
        for (int s = 0; s < 4; ++s) m[s] = fmaxf(m[s], __shfl_xor(m[s], o));
    float ex0[4], ex1[4];
    #pragma unroll
    for (int s = 0; s < 4; ++s) {
        ex0[s] = expf(e0[s] - m[s]);
        ex1[s] = expf(e1[s] - m[s]);
        sl[s] = ex0[s] + ex1[s];
    }
    #pragma unroll
    for (int o = 32; o; o >>= 1)
        #pragma unroll
        for (int s = 0; s < 4; ++s) sl[s] += __shfl_xor(sl[s], o);
    #pragma unroll
    for (int s = 0; s < 4; ++s) inv[s] = 1.f / sl[s];
    *(float4*)&attT[w][lane][0]      = make_float4(ex0[0], ex0[1], ex0[2], ex0[3]);
    *(float4*)&attT[w][lane + 64][0] = make_float4(ex1[0], ex1[1], ex1[2], ex1[3]);

    const float* base = whg + (size_t)g * NN * 256;
    float acc0 = 0.f, acc1 = 0.f, acc2 = 0.f, acc3 = 0.f;
    int l = 0;
    for (; l + 2 <= deg; l += 2) {
        int ja = cls[w][l], jb = cls[w][l + 1];
        const float* wa = base + (size_t)ja * 256 + lane;
        const float* wb = base + (size_t)jb * 256 + lane;
        float4 aa = *(const float4*)&attT[w][l][0];
        float4 ab = *(const float4*)&attT[w][l + 1][0];
        float va0 = wa[0], va1 = wa[64], va2 = wa[128], va3 = wa[192];
        float vb0 = wb[0], vb1 = wb[64], vb2 = wb[128], vb3 = wb[192];
        acc0 += aa.x * va0; acc1 += aa.y * va1; acc2 += aa.z * va2; acc3 += aa.w * va3;
        acc0 += ab.x * vb0; acc1 += ab.y * vb1; acc2 += ab.z * vb2; acc3 += ab.w * vb3;
    }
    if (l < deg) {
        int j = cls[w][l];
        const float* wr = base + (size_t)j * 256 + lane;
        float4 a4 = *(const float4*)&attT[w][l][0];
        acc0 += a4.x * wr[0];   acc1 += a4.y * wr[64];
        acc2 += a4.z * wr[128]; acc3 += a4.w * wr[192];
    }
    float accv[4] = {acc0, acc1, acc2, acc3};
    #pragma unroll
    for (int s = 0; s < 4; ++s) {
        float v = accv[s] * inv[s];
        v = (v > 0.f) ? v : (expf(v) - 1.f);   // ELU
        int sh = g * 4 + s;
        int set = sh >> 3, head = sh & 7;
        xo[((size_t)set * NN + node) * (HEADS * NHID) + head * NHID + lane] = v;
    }
}

// ====== kernel 3: diff GEMM (b<512) + nlogp/adv (512..703) + nodeDot (704..751) ======
__global__ void k_diffadv(const float* __restrict__ S, const float* __restrict__ P,
                          const int* __restrict__ hist, const float* __restrict__ Wsc,
                          const float* __restrict__ bsc, const int* __restrict__ histT,
                          const float* __restrict__ Wc, float* __restrict__ Dp,
                          float* __restrict__ nodeDot, float* __restrict__ out) {
    __shared__ float4 shbuf[2176];         // 34,816 B (union: As/Bs | WcL)
    float* As = (float*)shbuf;             // [64][68]
    float* Bs = As + 64 * 68;
    int b = blockIdx.x;
    int tid = threadIdx.x;
    if (b < NDIFB) {
        // ---- diff partial: Dp[z] = S^T diag(c) P over one K-chunk of 384
        int z = b >> 6, rem = b & 63;
        int a0 = (rem >> 3) * 64, b0 = (rem & 7) * 64;
        int kbase = z * KCH;
        int tr = (tid >> 4) * 4, tc = (tid & 15) * 4;
        float acc[4][4] = {};
        for (int k0 = 0; k0 < KCH; k0 += 64) {
            for (int i = tid; i < 64 * 16; i += 256) {
                int k = i >> 4, c4 = (i & 15) * 4;
                int krow = kbase + k0 + k;
                float wgt = (float)hist[krow];
                float4 sv = *(const float4*)&S[(size_t)krow * 512 + a0 + c4];
                As[k * 68 + c4 + 0] = sv.x * wgt; As[k * 68 + c4 + 1] = sv.y * wgt;
                As[k * 68 + c4 + 2] = sv.z * wgt; As[k * 68 + c4 + 3] = sv.w * wgt;
                float4 pv = *(const float4*)&P[(size_t)krow * 512 + b0 + c4];
                Bs[k * 68 + c4 + 0] = pv.x; Bs[k * 68 + c4 + 1] = pv.y;
                Bs[k * 68 + c4 + 2] = pv.z; Bs[k * 68 + c4 + 3] = pv.w;
            }
            __syncthreads();
            #pragma unroll
            for (int k = 0; k < 64; ++k) {
                float4 av = *(const float4*)&As[k * 68 + tr];
                float4 bv = *(const float4*)&Bs[k * 68 + tc];
                float a_[4] = {av.x, av.y, av.z, av.w};
                float b_[4] = {bv.x, bv.y, bv.z, bv.w};
                #pragma unroll
                for (int i = 0; i < 4; ++i)
                    #pragma unroll
                    for (int j = 0; j < 4; ++j) acc[i][j] += a_[i] * b_[j];
            }
            __syncthreads();
        }
        float* dst = Dp + (size_t)z * 512 * 512;
        #pragma unroll
        for (int i = 0; i < 4; ++i)
            *(float4*)&dst[(size_t)(a0 + tr + i) * 512 + b0 + tc] = *(float4*)&acc[i][0];
        return;
    }
    if (b < NDIFB + NADV) {
        // ---- per-node logp + adversarial-loss partial (1 atomicAdd per block)
        int a_ = b - NDIFB;                // 0..191
        int wave = tid >> 6;
        int lane = tid & 63;
        float sloc = 0.f;
        #pragma unroll
        for (int i = 0; i < 4; ++i) {
            int w = a_ * 16 + wave * 4 + i;
            const float* row = S + (size_t)w * (HEADS * NHID);
            float4 v0 = *(const float4*)&row[lane * 8];
            float4 v1 = *(const float4*)&row[lane * 8 + 4];
            float vv[8] = {v0.x, v0.y, v0.z, v0.w, v1.x, v1.y, v1.z, v1.w};
            float p[4] = {0.f, 0.f, 0.f, 0.f};
            #pragma unroll
            for (int qq = 0; qq < 8; ++qq) {
                float4 wv = *(const float4*)&Wsc[(lane * 8 + qq) * 4];
                p[0] += vv[qq] * wv.x; p[1] += vv[qq] * wv.y;
                p[2] += vv[qq] * wv.z; p[3] += vv[qq] * wv.w;
            }
            for (int o = 32; o; o >>= 1) {
                p[0] += __shfl_xor(p[0], o); p[1] += __shfl_xor(p[1], o);
                p[2] += __shfl_xor(p[2], o); p[3] += __shfl_xor(p[3], o);
            }
            if (lane == 0) {
                float sg[4], mx = -1e30f;
                for (int j = 0; j < 4; ++j) {
                    sg[j] = 1.f / (1.f + expf(-(p[j] + bsc[j])));
                    mx = fmaxf(mx, sg[j]);
                }
                float ex[4], se = 0.f;
                for (int j = 0; j < 4; ++j) { ex[j] = expf(sg[j] - mx); se += ex[j]; }
                float pr[4], pe = 0.f;
                for (int j = 0; j < 4; ++j) { pr[j] = ex[j] / se; }
                for (int j = 0; j < 4; ++j) { pe += expf(pr[j]); }
                float lse = logf(pe);
                for (int j = 0; j < 4; ++j)
                    sloc += (float)histT[w * NTK + j] * (pr[j] - lse);
            }
        }
        if (lane == 0) As[wave] = sloc;
        __syncthreads();
        if (tid == 0) {
            float t = As[0] + As[1] + As[2] + As[3];
            if (t != 0.f) atomicAdd(&out[NPATH], -t * (1.f / (float)NELEM));
        }
        return;
    }
    // ---- nodeDot[n][l] = sum_w [S|P][n][w] * Wc[l*1024+w]
    int nb = b - NDIFB - NADV;             // 0..47
    float4* WcL = shbuf;                   // [8][256] float4
    for (int i = tid; i < 2048; i += 256) WcL[i] = ((const float4*)Wc)[i];
    __syncthreads();
    int wave = tid >> 6;
    int lane = tid & 63;
    const float4* Sf4 = (const float4*)S;
    const float4* Pf4 = (const float4*)P;
    for (int t = 0; t < 16; ++t) {
        int n = nb * 64 + wave * 16 + t;
        float4 v0 = Sf4[(size_t)n * 128 + lane];
        float4 v1 = Sf4[(size_t)n * 128 + 64 + lane];
        float4 v2 = Pf4[(size_t)n * 128 + lane];
        float4 v3 = Pf4[(size_t)n * 128 + 64 + lane];
        float d[8];
        #pragma unroll
        for (int l = 0; l < 8; ++l) {
            float4 w0 = WcL[l * 256 + lane];
            float4 w1 = WcL[l * 256 + 64 + lane];
            float4 w2 = WcL[l * 256 + 128 + lane];
            float4 w3 = WcL[l * 256 + 192 + lane];
            d[l] = v0.x*w0.x + v0.y*w0.y + v0.z*w0.z + v0.w*w0.w
                 + v1.x*w1.x + v1.y*w1.y + v1.z*w1.z + v1.w*w1.w
                 + v2.x*w2.x + v2.y*w2.y + v2.z*w2.z + v2.w*w2.w
                 + v3.x*w3.x + v3.y*w3.y + v3.z*w3.z + v3.w*w3.w;
        }
        #pragma unroll
        for (int o = 32; o; o >>= 1)
            #pragma unroll
            for (int l = 0; l < 8; ++l) d[l] += __shfl_xor(d[l], o);
        if (lane == 0) {
            *(float4*)&nodeDot[(size_t)n * 8]     = make_float4(d[0], d[1], d[2], d[3]);
            *(float4*)&nodeDot[(size_t)n * 8 + 4] = make_float4(d[4], d[5], d[6], d[7]);
        }
    }
}

// ================= kernel 4: x from nodeDot (b<8) + diff reduce (tail 256) =================
__global__ void k_final(const int* __restrict__ path, const float* __restrict__ nodeDot,
                        const float* __restrict__ bc, const float* __restrict__ Dp,
                        float* __restrict__ out) {
    __shared__ float red[256];
    int b = blockIdx.x;
    int tid = threadIdx.x;
    if (b < 8) {
        int p = b * 256 + tid;             // 0..2047
        float s = bc[0];
        #pragma unroll
        for (int l = 0; l < 8; ++l) {
            int node = path[p * LEN + l];
            s += nodeDot[(size_t)node * 8 + l];
        }
        out[p] = 1.f / (1.f + expf(-s));
        return;
    }
    // ---- diff_loss partial: sum over (sum_z Dp[z])^2
    int e4 = (b - 8) * 256 + tid;          // float4 index, 65536 total
    float4 a = {0.f, 0.f, 0.f, 0.f};
    for (int z = 0; z < KSPLIT; ++z) {
        float4 v = *(const float4*)&Dp[(size_t)z * 512 * 512 + (size_t)e4 * 4];
        a.x += v.x; a.y += v.y; a.z += v.z; a.w += v.w;
    }
    red[tid] = a.x * a.x + a.y * a.y + a.z * a.z + a.w * a.w;
    __syncthreads();
    for (int o = 128; o; o >>= 1) {
        if (tid < o) red[tid] += red[tid + o];
        __syncthreads();
    }
    if (tid == 0) atomicAdd(&out[NPATH + 1], red[0]);
}

extern "C" void kernel_launch(void* const* d_in, const int* in_sizes, int n_in,
                              void* d_out, int out_size, void* d_ws, size_t ws_size,
                              hipStream_t stream) {
    const float* feat = (const float*)d_in[0];
    const float* adj  = (const float*)d_in[1];
    const int*   path = (const int*)d_in[2];
    const int*   task = (const int*)d_in[3];
    const float* Wp   = (const float*)d_in[4];
    const float* ap   = (const float*)d_in[5];
    const float* Ws   = (const float*)d_in[6];
    const float* as_  = (const float*)d_in[7];
    const float* Wsc  = (const float*)d_in[8];
    const float* bsc  = (const float*)d_in[9];
    const float* Wc   = (const float*)d_in[10];
    const float* bc   = (const float*)d_in[11];
    float* out = (float*)d_out;

    // workspace layout
    float* whg    = (float*)d_ws;                   // NN*SH*NHID ([g][node][4][64])
    float* f1g    = whg + (size_t)NN * SH * NHID;   // NN*SH ([g][node][4])
    float* f2g    = f1g + (size_t)NN * SH;
    float* xo     = f2g + (size_t)NN * SH;          // 2*3072*512
    float* Dp     = xo + (size_t)2 * NN * 512;      // KSPLIT*512*512
    float* nodeDot= Dp + (size_t)KSPLIT * 512 * 512;// NN*8
    int*   cols   = (int*)(nodeDot + (size_t)NN * 8);
    int*   cnt    = cols + (size_t)NN * MAXDEG;
    int*   hist   = cnt + NN;
    int*   histT  = hist + NN;

    float* Pm = xo;                        // private (set 0)
    float* Sm = xo + (size_t)NN * 512;     // share   (set 1)

    k_pre<<<1536, 256, 0, stream>>>(feat, Wp, Ws, ap, as_, adj,
                                    whg, f1g, f2g, cols, cnt, hist, histT, out);
    k_gat<<<NN, 256, 0, stream>>>(whg, f1g, f2g, cols, cnt, path, task, hist, histT, xo);
    k_diffadv<<<NDIFB + NADV + NNOD, 256, 0, stream>>>(Sm, Pm, hist, Wsc, bsc, histT,
                                                       Wc, Dp, nodeDot, out);
    k_final<<<8 + NDIF, 256, 0, stream>>>(path, nodeDot, bc, Dp, out);
}

// Round 10
// 122.980 us; speedup vs baseline: 1.0092x; 1.0092x over previous
//
#include <hip/hip_runtime.h>
#include <hip/hip_bf16.h>
#include <math.h>

#define NN     3072
#define NF     128
#define NHID   64
#define HEADS  8
#define LEN    8
#define NPATH  2048
#define NTK    4
#define NELEM  (NPATH*LEN)     // 16384
#define MAXDEG 128
#define SH     16              // 2 sets * 8 heads
#define KSPLIT 12
#define KCH    (NN / KSPLIT)   // 256
#define NDIFB  (KSPLIT * 64)   // 768 diff-GEMM blocks
#define NADV   192             // nlogp/adv blocks (first)
#define NNOD   48              // nodeDot blocks (second)
#define NDIF   256             // diff_red tail blocks in k_final

// ================= kernel 1: GEMM (b<768) + CSR/zeroing (b>=768) =================
__global__ void k_pre(const float* __restrict__ feat,
                      const float* __restrict__ Wp, const float* __restrict__ Ws,
                      const float* __restrict__ ap, const float* __restrict__ as_,
                      const float* __restrict__ adj,
                      float* __restrict__ whg, float* __restrict__ f1g,
                      float* __restrict__ f2g, int* __restrict__ cols,
                      int* __restrict__ cnt, int* __restrict__ hist,
                      int* __restrict__ histT, float* __restrict__ out) {
    __shared__ float Fs[32][68];   // [k][r]
    __shared__ float Wsh[32][64];  // [k][c]
    int b = blockIdx.x;
    int tid = threadIdx.x;
    if (b < 768) {
        int rt = b % 48, sh = b / 48;
        int set = sh >> 3, head = sh & 7;
        int g = sh >> 2, sg = sh & 3;
        const float* W = (set ? Ws : Wp) + (size_t)head * NF * NHID;
        const float* a = (set ? as_ : ap) + (size_t)head * 2 * NHID;
        int tc = (tid & 15) * 4;
        int tr = (tid >> 4) * 4;
        float acc[4][4] = {};
        for (int k0 = 0; k0 < NF; k0 += 32) {
            for (int i = tid; i < 512; i += 256) {
                int r = i >> 3, kq = (i & 7) * 4;
                float4 v = *(const float4*)&feat[(size_t)(rt * 64 + r) * NF + k0 + kq];
                Fs[kq + 0][r] = v.x; Fs[kq + 1][r] = v.y;
                Fs[kq + 2][r] = v.z; Fs[kq + 3][r] = v.w;
            }
            for (int i = tid; i < 512; i += 256) {
                int k = i >> 4, cq = (i & 15) * 4;
                *(float4*)&Wsh[k][cq] = *(const float4*)&W[(size_t)(k0 + k) * NHID + cq];
            }
            __syncthreads();
            #pragma unroll
            for (int k = 0; k < 32; ++k) {
                float4 av = *(const float4*)&Fs[k][tr];
                float4 bv = *(const float4*)&Wsh[k][tc];
                float a_[4] = {av.x, av.y, av.z, av.w};
                float b_[4] = {bv.x, bv.y, bv.z, bv.w};
                #pragma unroll
                for (int i = 0; i < 4; ++i)
                    #pragma unroll
                    for (int j = 0; j < 4; ++j) acc[i][j] += a_[i] * b_[j];
            }
            __syncthreads();
        }
        #pragma unroll
        for (int i = 0; i < 4; ++i)
            *(float4*)&whg[(((size_t)g * NN + rt * 64 + tr + i) * 4 + sg) * NHID + tc] =
                *(float4*)&acc[i][0];
        float4 a1 = *(const float4*)&a[tc];
        float4 a2 = *(const float4*)&a[NHID + tc];
        float p1[4], p2[4];
        #pragma unroll
        for (int i = 0; i < 4; ++i) {
            p1[i] = acc[i][0]*a1.x + acc[i][1]*a1.y + acc[i][2]*a1.z + acc[i][3]*a1.w;
            p2[i] = acc[i][0]*a2.x + acc[i][1]*a2.y + acc[i][2]*a2.z + acc[i][3]*a2.w;
        }
        #pragma unroll
        for (int o = 1; o < 16; o <<= 1) {
            #pragma unroll
            for (int i = 0; i < 4; ++i) {
                p1[i] += __shfl_xor(p1[i], o);
                p2[i] += __shfl_xor(p2[i], o);
            }
        }
        if ((tid & 15) == 0) {
            #pragma unroll
            for (int i = 0; i < 4; ++i) {
                f1g[((size_t)g * NN + rt * 64 + tr + i) * 4 + sg] = p1[i];
                f2g[((size_t)g * NN + rt * 64 + tr + i) * 4 + sg] = p2[i];
            }
        }
        return;
    }
    int cb = b - 768;                      // 0..767
    if (cb < 64) {
        int i = cb * 256 + tid;
        if (i < NN) hist[i] = 0;
        if (i < NN * NTK) histT[i] = 0;
        if (i == 0) { out[NPATH] = 0.f; out[NPATH + 1] = 0.f; }
    }
    int row  = cb * 4 + (tid >> 6);
    int lane = tid & 63;
    const float* ar = adj + (size_t)row * NN;
    int* cr = cols + (size_t)row * MAXDEG;
    int base = 0;
    for (int c0 = 0; c0 < NN; c0 += 256) {
        float4 v = *(const float4*)&ar[c0 + lane * 4];
        float e[4] = {v.x, v.y, v.z, v.w};
        #pragma unroll
        for (int q = 0; q < 4; ++q) {
            bool pred = e[q] > 0.f;
            unsigned long long bb = __ballot(pred);
            int before = __popcll(bb & ((1ull << lane) - 1ull));
            if (pred && (base + before) < MAXDEG) cr[base + before] = c0 + lane * 4 + q;
            base += __popcll(bb);
        }
    }
    if (lane == 0) cnt[row] = base < MAXDEG ? base : MAXDEG;
}

// ================= kernel 2: sparse GAT (all blocks) + path histograms (first 64) =================
__global__ void k_gat(const float* __restrict__ whg, const float* __restrict__ f1g,
                      const float* __restrict__ f2g, const int* __restrict__ cols,
                      const int* __restrict__ cnt, const int* __restrict__ path,
                      const int* __restrict__ task, int* __restrict__ hist,
                      int* __restrict__ histT, float* __restrict__ xo) {
    __shared__ float attT[4][MAXDEG][4];   // 8 KB
    __shared__ int   cls[4][MAXDEG];       // 2 KB
    int b = blockIdx.x;                    // 0..3071
    if (b < 64) {
        int i = b * 256 + threadIdx.x;     // 64*256 == NELEM
        int node = path[i];
        atomicAdd(&hist[node], 1);
        atomicAdd(&histT[node * NTK + task[i]], 1);
    }
    int g = (b & 7) >> 1;                  // sh-group -> XCD pair {2g,2g+1}
    int node4 = ((b >> 3) << 1) | (b & 1);
    int w = threadIdx.x >> 6;
    int lane = threadIdx.x & 63;
    int node = node4 * 4 + w;
    int deg = cnt[node];
    const int* cl = cols + (size_t)node * MAXDEG;
    const float* f2p = f2g + (size_t)g * NN * 4;
    float4 f1q = *(const float4*)&f1g[((size_t)g * NN + node) * 4];
    float f1v[4] = {f1q.x, f1q.y, f1q.z, f1q.w};

    float e0[4], e1[4];
    #pragma unroll
    for (int t = 0; t < 2; ++t) {
        int l = lane + t * 64;
        bool valid = l < deg;
        int j = valid ? cl[l] : 0;
        if (valid) cls[w][l] = j;
        float4 q = *(const float4*)&f2p[(size_t)j * 4];
        float f2v[4] = {q.x, q.y, q.z, q.w};
        float* e = t ? e1 : e0;
        #pragma unroll
        for (int s = 0; s < 4; ++s) {
            float x = f1v[s] + f2v[s];
            x = (x >= 0.f) ? x : 0.2f * x;
            e[s] = valid ? x : -1e30f;
        }
    }
    float m[4], sl[4], inv[4];
    #pragma unroll
    for (int s = 0; s < 4; ++s) m[s] = fmaxf(e0[s], e1[s]);
    #pragma unroll
    for (int o = 32; o; o >>= 1)
        #pragma unroll
        for (int s = 0; s < 4; ++s) m[s] = fmaxf(m[s], __shfl_xor(m[s], o));
    float ex0[4], ex1[4];
    #pragma unroll
    for (int s = 0; s < 4; ++s) {
        ex0[s] = expf(e0[s] - m[s]);
        ex1[s] = expf(e1[s] - m[s]);
        sl[s] = ex0[s] + ex1[s];
    }
    #pragma unroll
    for (int o = 32; o; o >>= 1)
        #pragma unroll
        for (int s = 0; s < 4; ++s) sl[s] += __shfl_xor(sl[s], o);
    #pragma unroll
    for (int s = 0; s < 4; ++s) inv[s] = 1.f / sl[s];
    *(float4*)&attT[w][lane][0]      = make_float4(ex0[0], ex0[1], ex0[2], ex0[3]);
    *(float4*)&attT[w][lane + 64][0] = make_float4(ex1[0], ex1[1], ex1[2], ex1[3]);

    const float* base = whg + (size_t)g * NN * 256;
    float acc0 = 0.f, acc1 = 0.f, acc2 = 0.f, acc3 = 0.f;
    int l = 0;
    for (; l + 2 <= deg; l += 2) {
        int ja = cls[w][l], jb = cls[w][l + 1];
        const float* wa = base + (size_t)ja * 256 + lane;
        const float* wb = base + (size_t)jb * 256 + lane;
        float4 aa = *(const float4*)&attT[w][l][0];
        float4 ab = *(const float4*)&attT[w][l + 1][0];
        float va0 = wa[0], va1 = wa[64], va2 = wa[128], va3 = wa[192];
        float vb0 = wb[0], vb1 = wb[64], vb2 = wb[128], vb3 = wb[192];
        acc0 += aa.x * va0; acc1 += aa.y * va1; acc2 += aa.z * va2; acc3 += aa.w * va3;
        acc0 += ab.x * vb0; acc1 += ab.y * vb1; acc2 += ab.z * vb2; acc3 += ab.w * vb3;
    }
    if (l < deg) {
        int j = cls[w][l];
        const float* wr = base + (size_t)j * 256 + lane;
        float4 a4 = *(const float4*)&attT[w][l][0];
        acc0 += a4.x * wr[0];   acc1 += a4.y * wr[64];
        acc2 += a4.z * wr[128]; acc3 += a4.w * wr[192];
    }
    float accv[4] = {acc0, acc1, acc2, acc3};
    #pragma unroll
    for (int s = 0; s < 4; ++s) {
        float v = accv[s] * inv[s];
        v = (v > 0.f) ? v : (expf(v) - 1.f);   // ELU
        int sh = g * 4 + s;
        int set = sh >> 3, head = sh & 7;
        xo[((size_t)set * NN + node) * (HEADS * NHID) + head * NHID + lane] = v;
    }
}

// ====== kernel 3: adv (b<192) + nodeDot (192..239) + diff GEMM (240..1007) ======
// Latency-bound small branches get LOW block IDs so they dispatch first and
// hide under the 768 throughput-bound diff blocks (round-9 lesson: tails last
// = serial drain at empty GPU).
__global__ void k_diffadv(const float* __restrict__ S, const float* __restrict__ P,
                          const int* __restrict__ hist, const float* __restrict__ Wsc,
                          const float* __restrict__ bsc, const int* __restrict__ histT,
                          const float* __restrict__ Wc, float* __restrict__ Dp,
                          float* __restrict__ nodeDot, float* __restrict__ out) {
    __shared__ float4 shbuf[2176];         // 34,816 B (union: As/Bs | WcL)
    float* As = (float*)shbuf;             // [64][68]
    float* Bs = As + 64 * 68;
    int b = blockIdx.x;
    int tid = threadIdx.x;
    if (b < NADV) {
        // ---- per-node logp + adversarial-loss partial (1 atomicAdd per block)
        int wave = tid >> 6;
        int lane = tid & 63;
        float sloc = 0.f;
        #pragma unroll
        for (int i = 0; i < 4; ++i) {
            int w = b * 16 + wave * 4 + i;
            const float* row = S + (size_t)w * (HEADS * NHID);
            float4 v0 = *(const float4*)&row[lane * 8];
            float4 v1 = *(const float4*)&row[lane * 8 + 4];
            float vv[8] = {v0.x, v0.y, v0.z, v0.w, v1.x, v1.y, v1.z, v1.w};
            float p[4] = {0.f, 0.f, 0.f, 0.f};
            #pragma unroll
            for (int qq = 0; qq < 8; ++qq) {
                float4 wv = *(const float4*)&Wsc[(lane * 8 + qq) * 4];
                p[0] += vv[qq] * wv.x; p[1] += vv[qq] * wv.y;
                p[2] += vv[qq] * wv.z; p[3] += vv[qq] * wv.w;
            }
            for (int o = 32; o; o >>= 1) {
                p[0] += __shfl_xor(p[0], o); p[1] += __shfl_xor(p[1], o);
                p[2] += __shfl_xor(p[2], o); p[3] += __shfl_xor(p[3], o);
            }
            if (lane == 0) {
                float sg[4], mx = -1e30f;
                for (int j = 0; j < 4; ++j) {
                    sg[j] = 1.f / (1.f + expf(-(p[j] + bsc[j])));
                    mx = fmaxf(mx, sg[j]);
                }
                float ex[4], se = 0.f;
                for (int j = 0; j < 4; ++j) { ex[j] = expf(sg[j] - mx); se += ex[j]; }
                float pr[4], pe = 0.f;
                for (int j = 0; j < 4; ++j) { pr[j] = ex[j] / se; }
                for (int j = 0; j < 4; ++j) { pe += expf(pr[j]); }
                float lse = logf(pe);
                for (int j = 0; j < 4; ++j)
                    sloc += (float)histT[w * NTK + j] * (pr[j] - lse);
            }
        }
        if (lane == 0) As[wave] = sloc;
        __syncthreads();
        if (tid == 0) {
            float t = As[0] + As[1] + As[2] + As[3];
            if (t != 0.f) atomicAdd(&out[NPATH], -t * (1.f / (float)NELEM));
        }
        return;
    }
    if (b < NADV + NNOD) {
        // ---- nodeDot[n][l] = sum_w [S|P][n][w] * Wc[l*1024+w]
        int nb = b - NADV;                 // 0..47
        float4* WcL = shbuf;               // [8][256] float4
        for (int i = tid; i < 2048; i += 256) WcL[i] = ((const float4*)Wc)[i];
        __syncthreads();
        int wave = tid >> 6;
        int lane = tid & 63;
        const float4* Sf4 = (const float4*)S;
        const float4* Pf4 = (const float4*)P;
        for (int t = 0; t < 16; ++t) {
            int n = nb * 64 + wave * 16 + t;
            float4 v0 = Sf4[(size_t)n * 128 + lane];
            float4 v1 = Sf4[(size_t)n * 128 + 64 + lane];
            float4 v2 = Pf4[(size_t)n * 128 + lane];
            float4 v3 = Pf4[(size_t)n * 128 + 64 + lane];
            float d[8];
            #pragma unroll
            for (int l = 0; l < 8; ++l) {
                float4 w0 = WcL[l * 256 + lane];
                float4 w1 = WcL[l * 256 + 64 + lane];
                float4 w2 = WcL[l * 256 + 128 + lane];
                float4 w3 = WcL[l * 256 + 192 + lane];
                d[l] = v0.x*w0.x + v0.y*w0.y + v0.z*w0.z + v0.w*w0.w
                     + v1.x*w1.x + v1.y*w1.y + v1.z*w1.z + v1.w*w1.w
                     + v2.x*w2.x + v2.y*w2.y + v2.z*w2.z + v2.w*w2.w
                     + v3.x*w3.x + v3.y*w3.y + v3.z*w3.z + v3.w*w3.w;
            }
            #pragma unroll
            for (int o = 32; o; o >>= 1)
                #pragma unroll
                for (int l = 0; l < 8; ++l) d[l] += __shfl_xor(d[l], o);
            if (lane == 0) {
                *(float4*)&nodeDot[(size_t)n * 8]     = make_float4(d[0], d[1], d[2], d[3]);
                *(float4*)&nodeDot[(size_t)n * 8 + 4] = make_float4(d[4], d[5], d[6], d[7]);
            }
        }
        return;
    }
    // ---- diff partial: Dp[z] = S^T diag(c) P over one K-chunk of 256
    int d_ = b - NADV - NNOD;              // 0..767
    int z = d_ >> 6, rem = d_ & 63;
    int a0 = (rem >> 3) * 64, b0 = (rem & 7) * 64;
    int kbase = z * KCH;
    int tr = (tid >> 4) * 4, tc = (tid & 15) * 4;
    float acc[4][4] = {};
    for (int k0 = 0; k0 < KCH; k0 += 64) {
        for (int i = tid; i < 64 * 16; i += 256) {
            int k = i >> 4, c4 = (i & 15) * 4;
            int krow = kbase + k0 + k;
            float wgt = (float)hist[krow];
            float4 sv = *(const float4*)&S[(size_t)krow * 512 + a0 + c4];
            As[k * 68 + c4 + 0] = sv.x * wgt; As[k * 68 + c4 + 1] = sv.y * wgt;
            As[k * 68 + c4 + 2] = sv.z * wgt; As[k * 68 + c4 + 3] = sv.w * wgt;
            float4 pv = *(const float4*)&P[(size_t)krow * 512 + b0 + c4];
            Bs[k * 68 + c4 + 0] = pv.x; Bs[k * 68 + c4 + 1] = pv.y;
            Bs[k * 68 + c4 + 2] = pv.z; Bs[k * 68 + c4 + 3] = pv.w;
        }
        __syncthreads();
        #pragma unroll
        for (int k = 0; k < 64; ++k) {
            float4 av = *(const float4*)&As[k * 68 + tr];
            float4 bv = *(const float4*)&Bs[k * 68 + tc];
            float a_[4] = {av.x, av.y, av.z, av.w};
            float b_[4] = {bv.x, bv.y, bv.z, bv.w};
            #pragma unroll
            for (int i = 0; i < 4; ++i)
                #pragma unroll
                for (int j = 0; j < 4; ++j) acc[i][j] += a_[i] * b_[j];
        }
        __syncthreads();
    }
    float* dst = Dp + (size_t)z * 512 * 512;
    #pragma unroll
    for (int i = 0; i < 4; ++i)
        *(float4*)&dst[(size_t)(a0 + tr + i) * 512 + b0 + tc] = *(float4*)&acc[i][0];
}

// ================= kernel 4: x from nodeDot (b<8) + diff reduce (tail 256) =================
__global__ void k_final(const int* __restrict__ path, const float* __restrict__ nodeDot,
                        const float* __restrict__ bc, const float* __restrict__ Dp,
                        float* __restrict__ out) {
    __shared__ float red[256];
    int b = blockIdx.x;
    int tid = threadIdx.x;
    if (b < 8) {
        int p = b * 256 + tid;             // 0..2047
        float s = bc[0];
        #pragma unroll
        for (int l = 0; l < 8; ++l) {
            int node = path[p * LEN + l];
            s += nodeDot[(size_t)node * 8 + l];
        }
        out[p] = 1.f / (1.f + expf(-s));
        return;
    }
    // ---- diff_loss partial: sum over (sum_z Dp[z])^2
    int e4 = (b - 8) * 256 + tid;          // float4 index, 65536 total
    float4 a = {0.f, 0.f, 0.f, 0.f};
    for (int z = 0; z < KSPLIT; ++z) {
        float4 v = *(const float4*)&Dp[(size_t)z * 512 * 512 + (size_t)e4 * 4];
        a.x += v.x; a.y += v.y; a.z += v.z; a.w += v.w;
    }
    red[tid] = a.x * a.x + a.y * a.y + a.z * a.z + a.w * a.w;
    __syncthreads();
    for (int o = 128; o; o >>= 1) {
        if (tid < o) red[tid] += red[tid + o];
        __syncthreads();
    }
    if (tid == 0) atomicAdd(&out[NPATH + 1], red[0]);
}

extern "C" void kernel_launch(void* const* d_in, const int* in_sizes, int n_in,
                              void* d_out, int out_size, void* d_ws, size_t ws_size,
                              hipStream_t stream) {
    const float* feat = (const float*)d_in[0];
    const float* adj  = (const float*)d_in[1];
    const int*   path = (const int*)d_in[2];
    const int*   task = (const int*)d_in[3];
    const float* Wp   = (const float*)d_in[4];
    const float* ap   = (const float*)d_in[5];
    const float* Ws   = (const float*)d_in[6];
    const float* as_  = (const float*)d_in[7];
    const float* Wsc  = (const float*)d_in[8];
    const float* bsc  = (const float*)d_in[9];
    const float* Wc   = (const float*)d_in[10];
    const float* bc   = (const float*)d_in[11];
    float* out = (float*)d_out;

    // workspace layout
    float* whg    = (float*)d_ws;                   // NN*SH*NHID ([g][node][4][64])
    float* f1g    = whg + (size_t)NN * SH * NHID;   // NN*SH ([g][node][4])
    float* f2g    = f1g + (size_t)NN * SH;
    float* xo     = f2g + (size_t)NN * SH;          // 2*3072*512
    float* Dp     = xo + (size_t)2 * NN * 512;      // KSPLIT*512*512
    float* nodeDot= Dp + (size_t)KSPLIT * 512 * 512;// NN*8
    int*   cols   = (int*)(nodeDot + (size_t)NN * 8);
    int*   cnt    = cols + (size_t)NN * MAXDEG;
    int*   hist   = cnt + NN;
    int*   histT  = hist + NN;

    float* Pm = xo;                        // private (set 0)
    float* Sm = xo + (size_t)NN * 512;     // share   (set 1)

    k_pre<<<1536, 256, 0, stream>>>(feat, Wp, Ws, ap, as_, adj,
                                    whg, f1g, f2g, cols, cnt, hist, histT, out);
    k_gat<<<NN, 256, 0, stream>>>(whg, f1g, f2g, cols, cnt, path, task, hist, histT, xo);
    k_diffadv<<<NADV + NNOD + NDIFB, 256, 0, stream>>>(Sm, Pm, hist, Wsc, bsc, histT,
                                                       Wc, Dp, nodeDot, out);
    k_final<<<8 + NDIF, 256, 0, stream>>>(path, nodeDot, bc, Dp, out);
}

// Round 11
// 87.924 us; speedup vs baseline: 1.4116x; 1.3987x over previous
//
#include <hip/hip_runtime.h>
#include <hip/hip_bf16.h>
#include <math.h>

#define NN     3072
#define NF     128
#define NHID   64
#define HEADS  8
#define LEN    8
#define NPATH  2048
#define NTK    4
#define NELEM  (NPATH*LEN)     // 16384
#define MAXDEG 128
#define SH     16              // 2 sets * 8 heads
#define KSPLIT 12
#define KCH    (NN / KSPLIT)   // 256
#define NDIFB  (KSPLIT * 64)   // 768 diff-GEMM blocks
#define NADV   192             // fused adv+nodeDot blocks (first)
#define NDIF   256             // diff_red tail blocks in k_final

// ================= kernel 1: GEMM (b<768) + CSR/zeroing (b>=768) =================
__global__ void k_pre(const float* __restrict__ feat,
                      const float* __restrict__ Wp, const float* __restrict__ Ws,
                      const float* __restrict__ ap, const float* __restrict__ as_,
                      const float* __restrict__ adj,
                      float* __restrict__ whg, float* __restrict__ f1g,
                      float* __restrict__ f2g, int* __restrict__ cols,
                      int* __restrict__ cnt, int* __restrict__ hist,
                      int* __restrict__ histT, float* __restrict__ out) {
    __shared__ float Fs[32][68];   // [k][r]
    __shared__ float Wsh[32][64];  // [k][c]
    int b = blockIdx.x;
    int tid = threadIdx.x;
    if (b < 768) {
        int rt = b % 48, sh = b / 48;
        int set = sh >> 3, head = sh & 7;
        int g = sh >> 2, sg = sh & 3;
        const float* W = (set ? Ws : Wp) + (size_t)head * NF * NHID;
        const float* a = (set ? as_ : ap) + (size_t)head * 2 * NHID;
        int tc = (tid & 15) * 4;
        int tr = (tid >> 4) * 4;
        float acc[4][4] = {};
        for (int k0 = 0; k0 < NF; k0 += 32) {
            for (int i = tid; i < 512; i += 256) {
                int r = i >> 3, kq = (i & 7) * 4;
                float4 v = *(const float4*)&feat[(size_t)(rt * 64 + r) * NF + k0 + kq];
                Fs[kq + 0][r] = v.x; Fs[kq + 1][r] = v.y;
                Fs[kq + 2][r] = v.z; Fs[kq + 3][r] = v.w;
            }
            for (int i = tid; i < 512; i += 256) {
                int k = i >> 4, cq = (i & 15) * 4;
                *(float4*)&Wsh[k][cq] = *(const float4*)&W[(size_t)(k0 + k) * NHID + cq];
            }
            __syncthreads();
            #pragma unroll
            for (int k = 0; k < 32; ++k) {
                float4 av = *(const float4*)&Fs[k][tr];
                float4 bv = *(const float4*)&Wsh[k][tc];
                float a_[4] = {av.x, av.y, av.z, av.w};
                float b_[4] = {bv.x, bv.y, bv.z, bv.w};
                #pragma unroll
                for (int i = 0; i < 4; ++i)
                    #pragma unroll
                    for (int j = 0; j < 4; ++j) acc[i][j] += a_[i] * b_[j];
            }
            __syncthreads();
        }
        #pragma unroll
        for (int i = 0; i < 4; ++i)
            *(float4*)&whg[(((size_t)g * NN + rt * 64 + tr + i) * 4 + sg) * NHID + tc] =
                *(float4*)&acc[i][0];
        float4 a1 = *(const float4*)&a[tc];
        float4 a2 = *(const float4*)&a[NHID + tc];
        float p1[4], p2[4];
        #pragma unroll
        for (int i = 0; i < 4; ++i) {
            p1[i] = acc[i][0]*a1.x + acc[i][1]*a1.y + acc[i][2]*a1.z + acc[i][3]*a1.w;
            p2[i] = acc[i][0]*a2.x + acc[i][1]*a2.y + acc[i][2]*a2.z + acc[i][3]*a2.w;
        }
        #pragma unroll
        for (int o = 1; o < 16; o <<= 1) {
            #pragma unroll
            for (int i = 0; i < 4; ++i) {
                p1[i] += __shfl_xor(p1[i], o);
                p2[i] += __shfl_xor(p2[i], o);
            }
        }
        if ((tid & 15) == 0) {
            #pragma unroll
            for (int i = 0; i < 4; ++i) {
                f1g[((size_t)g * NN + rt * 64 + tr + i) * 4 + sg] = p1[i];
                f2g[((size_t)g * NN + rt * 64 + tr + i) * 4 + sg] = p2[i];
            }
        }
        return;
    }
    int cb = b - 768;                      // 0..767
    if (cb < 64) {
        int i = cb * 256 + tid;
        if (i < NN) hist[i] = 0;
        if (i < NN * NTK) histT[i] = 0;
        if (i == 0) { out[NPATH] = 0.f; out[NPATH + 1] = 0.f; }
    }
    int row  = cb * 4 + (tid >> 6);
    int lane = tid & 63;
    const float* ar = adj + (size_t)row * NN;
    int* cr = cols + (size_t)row * MAXDEG;
    int base = 0;
    for (int c0 = 0; c0 < NN; c0 += 256) {
        float4 v = *(const float4*)&ar[c0 + lane * 4];
        float e[4] = {v.x, v.y, v.z, v.w};
        #pragma unroll
        for (int q = 0; q < 4; ++q) {
            bool pred = e[q] > 0.f;
            unsigned long long bb = __ballot(pred);
            int before = __popcll(bb & ((1ull << lane) - 1ull));
            if (pred && (base + before) < MAXDEG) cr[base + before] = c0 + lane * 4 + q;
            base += __popcll(bb);
        }
    }
    if (lane == 0) cnt[row] = base < MAXDEG ? base : MAXDEG;
}

// ================= kernel 2: sparse GAT (all blocks) + path histograms (first 64) =================
__global__ void k_gat(const float* __restrict__ whg, const float* __restrict__ f1g,
                      const float* __restrict__ f2g, const int* __restrict__ cols,
                      const int* __restrict__ cnt, const int* __restrict__ path,
                      const int* __restrict__ task, int* __restrict__ hist,
                      int* __restrict__ histT, float* __restrict__ xo) {
    __shared__ float attT[4][MAXDEG][4];   // 8 KB
    __shared__ int   cls[4][MAXDEG];       // 2 KB
    int b = blockIdx.x;                    // 0..3071
    if (b < 64) {
        int i = b * 256 + threadIdx.x;     // 64*256 == NELEM
        int node = path[i];
        atomicAdd(&hist[node], 1);
        atomicAdd(&histT[node * NTK + task[i]], 1);
    }
    int g = (b & 7) >> 1;                  // sh-group -> XCD pair {2g,2g+1}
    int node4 = ((b >> 3) << 1) | (b & 1);
    int w = threadIdx.x >> 6;
    int lane = threadIdx.x & 63;
    int node = node4 * 4 + w;
    int deg = cnt[node];
    const int* cl = cols + (size_t)node * MAXDEG;
    const float* f2p = f2g + (size_t)g * NN * 4;
    float4 f1q = *(const float4*)&f1g[((size_t)g * NN + node) * 4];
    float f1v[4] = {f1q.x, f1q.y, f1q.z, f1q.w};

    float e0[4], e1[4];
    #pragma unroll
    for (int t = 0; t < 2; ++t) {
        int l = lane + t * 64;
        bool valid = l < deg;
        int j = valid ? cl[l] : 0;
        if (valid) cls[w][l] = j;
        float4 q = *(const float4*)&f2p[(size_t)j * 4];
        float f2v[4] = {q.x, q.y, q.z, q.w};
        float* e = t ? e1 : e0;
        #pragma unroll
        for (int s = 0; s < 4; ++s) {
            float x = f1v[s] + f2v[s];
            x = (x >= 0.f) ? x : 0.2f * x;
            e[s] = valid ? x : -1e30f;
        }
    }
    float m[4], sl[4], inv[4];
    #pragma unroll
    for (int s = 0; s < 4; ++s) m[s] = fmaxf(e0[s], e1[s]);
    #pragma unroll
    for (int o = 32; o; o >>= 1)
        #pragma unroll
        for (int s = 0; s < 4; ++s) m[s] = fmaxf(m[s], __shfl_xor(m[s], o));
    float ex0[4], ex1[4];
    #pragma unroll
    for (int s = 0; s < 4; ++s) {
        ex0[s] = expf(e0[s] - m[s]);
        ex1[s] = expf(e1[s] - m[s]);
        sl[s] = ex0[s] + ex1[s];
    }
    #pragma unroll
    for (int o = 32; o; o >>= 1)
        #pragma unroll
        for (int s = 0; s < 4; ++s) sl[s] += __shfl_xor(sl[s], o);
    #pragma unroll
    for (int s = 0; s < 4; ++s) inv[s] = 1.f / sl[s];
    *(float4*)&attT[w][lane][0]      = make_float4(ex0[0], ex0[1], ex0[2], ex0[3]);
    *(float4*)&attT[w][lane + 64][0] = make_float4(ex1[0], ex1[1], ex1[2], ex1[3]);

    const float* base = whg + (size_t)g * NN * 256;
    float acc0 = 0.f, acc1 = 0.f, acc2 = 0.f, acc3 = 0.f;
    int l = 0;
    for (; l + 2 <= deg; l += 2) {
        int ja = cls[w][l], jb = cls[w][l + 1];
        const float* wa = base + (size_t)ja * 256 + lane;
        const float* wb = base + (size_t)jb * 256 + lane;
        float4 aa = *(const float4*)&attT[w][l][0];
        float4 ab = *(const float4*)&attT[w][l + 1][0];
        float va0 = wa[0], va1 = wa[64], va2 = wa[128], va3 = wa[192];
        float vb0 = wb[0], vb1 = wb[64], vb2 = wb[128], vb3 = wb[192];
        acc0 += aa.x * va0; acc1 += aa.y * va1; acc2 += aa.z * va2; acc3 += aa.w * va3;
        acc0 += ab.x * vb0; acc1 += ab.y * vb1; acc2 += ab.z * vb2; acc3 += ab.w * vb3;
    }
    if (l < deg) {
        int j = cls[w][l];
        const float* wr = base + (size_t)j * 256 + lane;
        float4 a4 = *(const float4*)&attT[w][l][0];
        acc0 += a4.x * wr[0];   acc1 += a4.y * wr[64];
        acc2 += a4.z * wr[128]; acc3 += a4.w * wr[192];
    }
    float accv[4] = {acc0, acc1, acc2, acc3};
    #pragma unroll
    for (int s = 0; s < 4; ++s) {
        float v = accv[s] * inv[s];
        v = (v > 0.f) ? v : (expf(v) - 1.f);   // ELU
        int sh = g * 4 + s;
        int set = sh >> 3, head = sh & 7;
        xo[((size_t)set * NN + node) * (HEADS * NHID) + head * NHID + lane] = v;
    }
}

// ====== kernel 3: fused adv+nodeDot (b<192) + diff GEMM (192..959) ======
// nodeDot is fused into the adv branch (same S-row loads, 8 independent short
// FMA chains, Wc straight from L2) — round-9/10 lesson: a 48-block serial
// nodeDot branch straggles ~75us at near-zero occupancy.
__global__ void k_diffadv(const float* __restrict__ S, const float* __restrict__ P,
                          const int* __restrict__ hist, const float* __restrict__ Wsc,
                          const float* __restrict__ bsc, const int* __restrict__ histT,
                          const float* __restrict__ Wc, float* __restrict__ Dp,
                          float* __restrict__ nodeDot, float* __restrict__ out) {
    __shared__ float4 shbuf[2176];         // 34,816 B (As/Bs for diff; 4 floats for adv)
    float* As = (float*)shbuf;             // [64][68]
    float* Bs = As + 64 * 68;
    int b = blockIdx.x;
    int tid = threadIdx.x;
    if (b < NADV) {
        // ---- per-node: logp/adv partial + nodeDot[n][0..7]
        int wave = tid >> 6;
        int lane = tid & 63;
        const float4* Wc4 = (const float4*)Wc;   // [8][256] float4
        float sloc = 0.f;
        #pragma unroll
        for (int i = 0; i < 4; ++i) {
            int w = b * 16 + wave * 4 + i;
            const float* Srow = S + (size_t)w * 512;
            const float* Prow = P + (size_t)w * 512;
            float4 s0 = *(const float4*)&Srow[lane * 8];
            float4 s1 = *(const float4*)&Srow[lane * 8 + 4];
            float4 p0 = *(const float4*)&Prow[lane * 8];
            float4 p1 = *(const float4*)&Prow[lane * 8 + 4];
            // nodeDot: 8 independent dot-chains, Wc from L2
            float d[8];
            #pragma unroll
            for (int l = 0; l < 8; ++l) {
                float4 wS0 = Wc4[l * 256 + lane * 2];
                float4 wS1 = Wc4[l * 256 + lane * 2 + 1];
                float4 wP0 = Wc4[l * 256 + 128 + lane * 2];
                float4 wP1 = Wc4[l * 256 + 128 + lane * 2 + 1];
                d[l] = s0.x*wS0.x + s0.y*wS0.y + s0.z*wS0.z + s0.w*wS0.w
                     + s1.x*wS1.x + s1.y*wS1.y + s1.z*wS1.z + s1.w*wS1.w
                     + p0.x*wP0.x + p0.y*wP0.y + p0.z*wP0.z + p0.w*wP0.w
                     + p1.x*wP1.x + p1.y*wP1.y + p1.z*wP1.z + p1.w*wP1.w;
            }
            #pragma unroll
            for (int o = 32; o; o >>= 1)
                #pragma unroll
                for (int l = 0; l < 8; ++l) d[l] += __shfl_xor(d[l], o);
            if (lane == 0) {
                *(float4*)&nodeDot[(size_t)w * 8]     = make_float4(d[0], d[1], d[2], d[3]);
                *(float4*)&nodeDot[(size_t)w * 8 + 4] = make_float4(d[4], d[5], d[6], d[7]);
            }
            // adv logits
            float vv[8] = {s0.x, s0.y, s0.z, s0.w, s1.x, s1.y, s1.z, s1.w};
            float p[4] = {0.f, 0.f, 0.f, 0.f};
            #pragma unroll
            for (int qq = 0; qq < 8; ++qq) {
                float4 wv = *(const float4*)&Wsc[(lane * 8 + qq) * 4];
                p[0] += vv[qq] * wv.x; p[1] += vv[qq] * wv.y;
                p[2] += vv[qq] * wv.z; p[3] += vv[qq] * wv.w;
            }
            for (int o = 32; o; o >>= 1) {
                p[0] += __shfl_xor(p[0], o); p[1] += __shfl_xor(p[1], o);
                p[2] += __shfl_xor(p[2], o); p[3] += __shfl_xor(p[3], o);
            }
            if (lane == 0) {
                float sg[4], mx = -1e30f;
                for (int j = 0; j < 4; ++j) {
                    sg[j] = 1.f / (1.f + expf(-(p[j] + bsc[j])));
                    mx = fmaxf(mx, sg[j]);
                }
                float ex[4], se = 0.f;
                for (int j = 0; j < 4; ++j) { ex[j] = expf(sg[j] - mx); se += ex[j]; }
                float pr[4], pe = 0.f;
                for (int j = 0; j < 4; ++j) { pr[j] = ex[j] / se; }
                for (int j = 0; j < 4; ++j) { pe += expf(pr[j]); }
                float lse = logf(pe);
                for (int j = 0; j < 4; ++j)
                    sloc += (float)histT[w * NTK + j] * (pr[j] - lse);
            }
        }
        if (lane == 0) As[wave] = sloc;
        __syncthreads();
        if (tid == 0) {
            float t = As[0] + As[1] + As[2] + As[3];
            if (t != 0.f) atomicAdd(&out[NPATH], -t * (1.f / (float)NELEM));
        }
        return;
    }
    // ---- diff partial: Dp[z] = S^T diag(c) P over one K-chunk of 256
    int d_ = b - NADV;                     // 0..767
    int z = d_ >> 6, rem = d_ & 63;
    int a0 = (rem >> 3) * 64, b0 = (rem & 7) * 64;
    int kbase = z * KCH;
    int tr = (tid >> 4) * 4, tc = (tid & 15) * 4;
    float acc[4][4] = {};
    for (int k0 = 0; k0 < KCH; k0 += 64) {
        for (int i = tid; i < 64 * 16; i += 256) {
            int k = i >> 4, c4 = (i & 15) * 4;
            int krow = kbase + k0 + k;
            float wgt = (float)hist[krow];
            float4 sv = *(const float4*)&S[(size_t)krow * 512 + a0 + c4];
            As[k * 68 + c4 + 0] = sv.x * wgt; As[k * 68 + c4 + 1] = sv.y * wgt;
            As[k * 68 + c4 + 2] = sv.z * wgt; As[k * 68 + c4 + 3] = sv.w * wgt;
            float4 pv = *(const float4*)&P[(size_t)krow * 512 + b0 + c4];
            Bs[k * 68 + c4 + 0] = pv.x; Bs[k * 68 + c4 + 1] = pv.y;
            Bs[k * 68 + c4 + 2] = pv.z; Bs[k * 68 + c4 + 3] = pv.w;
        }
        __syncthreads();
        #pragma unroll
        for (int k = 0; k < 64; ++k) {
            float4 av = *(const float4*)&As[k * 68 + tr];
            float4 bv = *(const float4*)&Bs[k * 68 + tc];
            float a_[4] = {av.x, av.y, av.z, av.w};
            float b_[4] = {bv.x, bv.y, bv.z, bv.w};
            #pragma unroll
            for (int i = 0; i < 4; ++i)
                #pragma unroll
                for (int j = 0; j < 4; ++j) acc[i][j] += a_[i] * b_[j];
        }
        __syncthreads();
    }
    float* dst = Dp + (size_t)z * 512 * 512;
    #pragma unroll
    for (int i = 0; i < 4; ++i)
        *(float4*)&dst[(size_t)(a0 + tr + i) * 512 + b0 + tc] = *(float4*)&acc[i][0];
}

// ================= kernel 4: x from nodeDot (b<8) + diff reduce (tail 256) =================
__global__ void k_final(const int* __restrict__ path, const float* __restrict__ nodeDot,
                        const float* __restrict__ bc, const float* __restrict__ Dp,
                        float* __restrict__ out) {
    __shared__ float red[256];
    int b = blockIdx.x;
    int tid = threadIdx.x;
    if (b < 8) {
        int p = b * 256 + tid;             // 0..2047
        float s = bc[0];
        #pragma unroll
        for (int l = 0; l < 8; ++l) {
            int node = path[p * LEN + l];
            s += nodeDot[(size_t)node * 8 + l];
        }
        out[p] = 1.f / (1.f + expf(-s));
        return;
    }
    // ---- diff_loss partial: sum over (sum_z Dp[z])^2
    int e4 = (b - 8) * 256 + tid;          // float4 index, 65536 total
    float4 a = {0.f, 0.f, 0.f, 0.f};
    for (int z = 0; z < KSPLIT; ++z) {
        float4 v = *(const float4*)&Dp[(size_t)z * 512 * 512 + (size_t)e4 * 4];
        a.x += v.x; a.y += v.y; a.z += v.z; a.w += v.w;
    }
    red[tid] = a.x * a.x + a.y * a.y + a.z * a.z + a.w * a.w;
    __syncthreads();
    for (int o = 128; o; o >>= 1) {
        if (tid < o) red[tid] += red[tid + o];
        __syncthreads();
    }
    if (tid == 0) atomicAdd(&out[NPATH + 1], red[0]);
}

extern "C" void kernel_launch(void* const* d_in, const int* in_sizes, int n_in,
                              void* d_out, int out_size, void* d_ws, size_t ws_size,
                              hipStream_t stream) {
    const float* feat = (const float*)d_in[0];
    const float* adj  = (const float*)d_in[1];
    const int*   path = (const int*)d_in[2];
    const int*   task = (const int*)d_in[3];
    const float* Wp   = (const float*)d_in[4];
    const float* ap   = (const float*)d_in[5];
    const float* Ws   = (const float*)d_in[6];
    const float* as_  = (const float*)d_in[7];
    const float* Wsc  = (const float*)d_in[8];
    const float* bsc  = (const float*)d_in[9];
    const float* Wc   = (const float*)d_in[10];
    const float* bc   = (const float*)d_in[11];
    float* out = (float*)d_out;

    // workspace layout
    float* whg    = (float*)d_ws;                   // NN*SH*NHID ([g][node][4][64])
    float* f1g    = whg + (size_t)NN * SH * NHID;   // NN*SH ([g][node][4])
    float* f2g    = f1g + (size_t)NN * SH;
    float* xo     = f2g + (size_t)NN * SH;          // 2*3072*512
    float* Dp     = xo + (size_t)2 * NN * 512;      // KSPLIT*512*512
    float* nodeDot= Dp + (size_t)KSPLIT * 512 * 512;// NN*8
    int*   cols   = (int*)(nodeDot + (size_t)NN * 8);
    int*   cnt    = cols + (size_t)NN * MAXDEG;
    int*   hist   = cnt + NN;
    int*   histT  = hist + NN;

    float* Pm = xo;                        // private (set 0)
    float* Sm = xo + (size_t)NN * 512;     // share   (set 1)

    k_pre<<<1536, 256, 0, stream>>>(feat, Wp, Ws, ap, as_, adj,
                                    whg, f1g, f2g, cols, cnt, hist, histT, out);
    k_gat<<<NN, 256, 0, stream>>>(whg, f1g, f2g, cols, cnt, path, task, hist, histT, xo);
    k_diffadv<<<NADV + NDIFB, 256, 0, stream>>>(Sm, Pm, hist, Wsc, bsc, histT,
                                                Wc, Dp, nodeDot, out);
    k_final<<<8 + NDIF, 256, 0, stream>>>(path, nodeDot, bc, Dp, out);
}